// Round 4
// baseline (201.572 us; speedup 1.0000x reference)
//
#include <hip/hip_runtime.h>

#define B_  8
#define QL_ 128
#define ML_ 1024
#define KS_ 512
#define H_  256

// ws layout (floats):
//   Eq = exp2(2log2e*qproj): [B][QL][H]   @ 0        (262144 floats)
//   Ek = exp2(2log2e*kproj): [B][ML][H]   @ 262144   (2097152 floats)
//   mask canonical uint8 [B*ML]           @ 2359296  (8192 B = 2048 floats)
//   Whi bf16 [512][512]                   @ 2361344  (131072 floats)
//   Wlo bf16 [512][512]                   @ 2492416  (131072 floats)
//   Xhi bf16 [9216][512]                  @ 2623488  (2359296 floats)
//   Xlo bf16 [9216][512]                  @ 4982784  (2359296 floats)
#define QP_OFF 0
#define KP_OFF 262144
#define MASK_OFF 2359296
#define WH_OFF 2361344
#define WL_OFF 2492416
#define XH_OFF 2623488
#define XL_OFF 4982784

typedef __attribute__((ext_vector_type(8))) short bfrag;   // 8 bf16 (4 VGPR)
typedef __attribute__((ext_vector_type(4))) float f4acc;   // MFMA acc

// fp32 -> (hi,lo) bf16 split. hi = truncation (residual <= 2^-8|x|, captured
// exactly by fp32 subtract); lo = RNE of residual (final err <= 2^-17|x|).
// Dropped lo*lo cross term <= 2^-16 rel. Same math as R2/R3 (bit-identical).
__device__ __forceinline__ void split1(float v, unsigned& h, unsigned& lo) {
    unsigned u  = __float_as_uint(v);
    unsigned hb = u & 0xFFFF0000u;
    float    lf = v - __uint_as_float(hb);           // exact
    unsigned ul = __float_as_uint(lf);
    unsigned lr = ul + 0x7FFFu + ((ul >> 16) & 1u);  // RNE
    h  = u >> 16;
    lo = lr >> 16;
}

__device__ __forceinline__ void split4(const float4& a, unsigned& h01, unsigned& h23,
                                       unsigned& l01, unsigned& l23) {
    unsigned h[4], l[4];
    split1(a.x, h[0], l[0]); split1(a.y, h[1], l[1]);
    split1(a.z, h[2], l[2]); split1(a.w, h[3], l[3]);
    h01 = h[0] | (h[1] << 16); h23 = h[2] | (h[3] << 16);
    l01 = l[0] | (l[1] << 16); l23 = l[2] | (l[3] << 16);
}

// ---------------------------------------------------------------------------
// Prep kernel: one-time bf16 hi/lo split of W (1 MB) AND X=query|memory
// (18.9 MB) + mask canonicalizer. Memory-bound (~38 MB moved, ~6 us).
// Pre-splitting X removes ALL VALU + LDS + barriers from proj's main loop
// (R3's proj was stuck ~46 us: 1-phase prefetch distance < L2 latency and
// barrier-lockstep at 2.25 waves/SIMD).
// Grid 1217 x 256:
//   bid 0..31    : Wq -> Whi/Wlo rows 0..255
//   bid 32..63   : Wk -> Whi/Wlo rows 256..511
//   bid 64..191  : query  -> Xhi/Xlo shorts [0, 524288)
//   bid 192..1215: memory -> Xhi/Xlo shorts [524288, 4718592)
//   bid 1216     : mask canonicalizer
// Each thread: 16 contiguous floats (4 float4 loads -> 2+2 uint4 stores).
// ---------------------------------------------------------------------------
__global__ __launch_bounds__(256) void prep_kernel(
    const float* __restrict__ query, const float* __restrict__ memory,
    const float* __restrict__ Wq, const float* __restrict__ Wk,
    unsigned short* __restrict__ Whi, unsigned short* __restrict__ Wlo,
    unsigned short* __restrict__ Xhi, unsigned short* __restrict__ Xlo,
    const unsigned char* __restrict__ mraw, unsigned char* __restrict__ mout) {
    const int bid = blockIdx.x;
    const int t = threadIdx.x;

    if (bid == 1216) {   // ---- mask canonicalizer ----
        __shared__ int s_not01, s_not0f;
        const unsigned int* w = (const unsigned int*)mraw;
        if (t == 0) { s_not01 = 0; s_not0f = 0; }
        __syncthreads();
        int not01 = 0, not0f = 0;
        for (int i = t; i < 2048; i += 256) {
            unsigned int v = w[i];
            if (v != 0u && v != 1u) not01 = 1;
            if (v != 0u && v != 0x3F800000u) not0f = 1;
        }
        if (not01) atomicOr(&s_not01, 1);
        if (not0f) atomicOr(&s_not0f, 1);
        __syncthreads();
        int wordTyped = (!s_not01) || (!s_not0f);
        for (int i = t; i < B_ * ML_; i += 256) {
            unsigned char mv;
            if (wordTyped) mv = (w[i] != 0u) ? 1 : 0;
            else           mv = mraw[i] ? 1 : 0;
            mout[i] = mv;
        }
        return;
    }

    const float* src; unsigned short *dh, *dl; size_t soff, doff;
    if (bid < 64) {
        src = (bid < 32) ? Wq : Wk;
        soff = (size_t)(bid & 31) * 4096;
        doff = ((bid < 32) ? 0 : 131072) + soff;
        dh = Whi; dl = Wlo;
    } else if (bid < 192) {
        src = query;  soff = (size_t)(bid - 64) * 4096;  doff = soff;
        dh = Xhi; dl = Xlo;
    } else {
        src = memory; soff = (size_t)(bid - 192) * 4096; doff = 524288 + soff;
        dh = Xhi; dl = Xlo;
    }
    soff += (size_t)t * 16; doff += (size_t)t * 16;

    unsigned hw[8], lw[8];
#pragma unroll
    for (int i = 0; i < 4; ++i) {
        float4 v = *(const float4*)(src + soff + i * 4);
        split4(v, hw[i * 2], hw[i * 2 + 1], lw[i * 2], lw[i * 2 + 1]);
    }
    *(uint4*)(dh + doff)     = make_uint4(hw[0], hw[1], hw[2], hw[3]);
    *(uint4*)(dh + doff + 8) = make_uint4(hw[4], hw[5], hw[6], hw[7]);
    *(uint4*)(dl + doff)     = make_uint4(lw[0], lw[1], lw[2], lw[3]);
    *(uint4*)(dl + doff + 8) = make_uint4(lw[4], lw[5], lw[6], lw[7]);
}

// ---------------------------------------------------------------------------
// Projection via bf16x3-split MFMA. Pure load+MFMA: NO LDS, NO barriers,
// NO VALU in the K-loop (both operands pre-split by prep_kernel).
// Grid 576 x 256: work id wk (XCD-chunked bijective swizzle, 576 = 8*72):
//   nb = wk&3 (n quadrant of 64), mb = wk>>2 (m tile of 64; <16 q, else mem).
// Block = 64m x 64n; wave (wm,wn) owns 32m x 32n; per wave 2x2 16x16 frags,
// acc 16 VGPR. Each lane global-loads its OWN frag source (frag layout
// m89-family: A lane l -> row l&15, k = 8*(l>>4)+j contiguous; C/D col=l&15,
// row=(l>>4)*4+reg). Double-buffered register prefetch; waves slip freely
// (no lockstep) so L2 latency is hidden by TLP + MFMA.
// Same split + same MFMA accumulation order as R2/R3 -> bit-identical out.
// ---------------------------------------------------------------------------
__global__ __launch_bounds__(256) void proj_kernel(
    const unsigned short* __restrict__ Xhi, const unsigned short* __restrict__ Xlo,
    const unsigned short* __restrict__ Whi, const unsigned short* __restrict__ Wlo,
    const float* __restrict__ bq, const float* __restrict__ bk,
    float* __restrict__ Eq, float* __restrict__ Ek) {
    const int bid = blockIdx.x;
    const int t = threadIdx.x;
    // XCD swizzle: XCD r gets contiguous work [72r, 72r+72) -> the 4 n-blocks
    // sharing A-rows land on the same XCD's L2.
    const int wk = (bid & 7) * 72 + (bid >> 3);
    const int nb = wk & 3;
    const int mb = wk >> 2;          // 0..143

    const bool isQ = (mb < 16);
    const int arow0 = mb * 64;                        // row in X planes (global)
    const int orow0 = isQ ? mb * 64 : mb * 64 - 1024; // row in output
    const float* bias = isQ ? bq : bk;
    float* out = isQ ? Eq : Ek;
    const int wrb = (isQ ? 0 : 256) + nb * 64;        // W-plane row base

    const int w  = t >> 6;
    const int wm = w >> 1, wn = w & 1;
    const int l  = t & 63;
    const int lr = l & 15;    // frag row/col within 16-tile
    const int lk = l >> 4;    // k-group (8 els) within 32-chunk

    const unsigned short* pah0 = Xhi + (size_t)(arow0 + wm * 32 +  0 + lr) * 512 + lk * 8;
    const unsigned short* pah1 = Xhi + (size_t)(arow0 + wm * 32 + 16 + lr) * 512 + lk * 8;
    const unsigned short* pal0 = Xlo + (size_t)(arow0 + wm * 32 +  0 + lr) * 512 + lk * 8;
    const unsigned short* pal1 = Xlo + (size_t)(arow0 + wm * 32 + 16 + lr) * 512 + lk * 8;
    const unsigned short* pbh0 = Whi + (size_t)(wrb + wn * 32 +  0 + lr) * 512 + lk * 8;
    const unsigned short* pbh1 = Whi + (size_t)(wrb + wn * 32 + 16 + lr) * 512 + lk * 8;
    const unsigned short* pbl0 = Wlo + (size_t)(wrb + wn * 32 +  0 + lr) * 512 + lk * 8;
    const unsigned short* pbl1 = Wlo + (size_t)(wrb + wn * 32 + 16 + lr) * 512 + lk * 8;

    f4acc acc[2][2];
#pragma unroll
    for (int mi = 0; mi < 2; ++mi)
#pragma unroll
        for (int ni = 0; ni < 2; ++ni)
            acc[mi][ni] = (f4acc){0.f, 0.f, 0.f, 0.f};

    uint4 s0ah0, s0ah1, s0al0, s0al1, s0bh0, s0bh1, s0bl0, s0bl1;
    uint4 s1ah0, s1ah1, s1al0, s1al1, s1bh0, s1bh1, s1bl0, s1bl1;

#define LDSET(P, c) do {                                              \
    P##ah0 = *(const uint4*)(pah0 + (size_t)(c) * 32);                \
    P##ah1 = *(const uint4*)(pah1 + (size_t)(c) * 32);                \
    P##al0 = *(const uint4*)(pal0 + (size_t)(c) * 32);                \
    P##al1 = *(const uint4*)(pal1 + (size_t)(c) * 32);                \
    P##bh0 = *(const uint4*)(pbh0 + (size_t)(c) * 32);                \
    P##bh1 = *(const uint4*)(pbh1 + (size_t)(c) * 32);                \
    P##bl0 = *(const uint4*)(pbl0 + (size_t)(c) * 32);                \
    P##bl1 = *(const uint4*)(pbl1 + (size_t)(c) * 32); } while (0)

#define COMPSET(P) do {                                               \
    bfrag ah[2], al[2], bh[2], bl[2];                                 \
    ah[0] = __builtin_bit_cast(bfrag, P##ah0);                        \
    ah[1] = __builtin_bit_cast(bfrag, P##ah1);                        \
    al[0] = __builtin_bit_cast(bfrag, P##al0);                        \
    al[1] = __builtin_bit_cast(bfrag, P##al1);                        \
    bh[0] = __builtin_bit_cast(bfrag, P##bh0);                        \
    bh[1] = __builtin_bit_cast(bfrag, P##bh1);                        \
    bl[0] = __builtin_bit_cast(bfrag, P##bl0);                        \
    bl[1] = __builtin_bit_cast(bfrag, P##bl1);                        \
    _Pragma("unroll")                                                 \
    for (int mi = 0; mi < 2; ++mi)                                    \
    _Pragma("unroll")                                                 \
    for (int ni = 0; ni < 2; ++ni) {                                  \
        acc[mi][ni] = __builtin_amdgcn_mfma_f32_16x16x32_bf16(        \
            ah[mi], bh[ni], acc[mi][ni], 0, 0, 0);                    \
        acc[mi][ni] = __builtin_amdgcn_mfma_f32_16x16x32_bf16(        \
            ah[mi], bl[ni], acc[mi][ni], 0, 0, 0);                    \
        acc[mi][ni] = __builtin_amdgcn_mfma_f32_16x16x32_bf16(        \
            al[mi], bh[ni], acc[mi][ni], 0, 0, 0);                    \
    } } while (0)

    LDSET(s0, 0);
    LDSET(s1, 1);
#pragma unroll
    for (int c2 = 0; c2 < 8; ++c2) {
        COMPSET(s0);
        if (c2 < 7) LDSET(s0, 2 * c2 + 2);
        COMPSET(s1);
        if (c2 < 7) LDSET(s1, 2 * c2 + 3);
    }
#undef LDSET
#undef COMPSET

    // epilogue: bias + exp2, dword stores (lanes 0-15 contiguous cols)
    const float SC = 2.885390081777926815f;   // 2*log2(e)
    float bcol[2];
#pragma unroll
    for (int ni = 0; ni < 2; ++ni) bcol[ni] = bias[nb * 64 + wn * 32 + ni * 16 + lr];

#pragma unroll
    for (int mi = 0; mi < 2; ++mi)
#pragma unroll
        for (int ni = 0; ni < 2; ++ni) {
            const int col = nb * 64 + wn * 32 + ni * 16 + lr;
#pragma unroll
            for (int r = 0; r < 4; ++r) {
                const int row = orow0 + wm * 32 + mi * 16 + lk * 4 + r;
                out[(size_t)row * 256 + col] =
                    __builtin_amdgcn_exp2f(SC * (acc[mi][ni][r] + bcol[ni]));
            }
        }
}

// ---------------------------------------------------------------------------
// sr[b][q][m] = sum_h wl[h] / (Eq[b][q][h]*Ek[b][m][h] + 1)
// (tanh folded; exp precomputed). 4-way reciprocal grouping: 1 rcp per 4 h.
// R3 counters: 43 us, VALUBusy 56%, HBM 2.6%, conflicts 0 -> LDS-PORT-bound:
// 6 ds_read_b128 per quad (k4 + 4 q4 + w4) = 72 cyc/wave/quad vs 112 cyc
// VALU, 4 waves sharing one LDS. q4/w4 are WAVE-UNIFORM -> move them to
// global (readfirstlane'd base -> scalar/K$ path, L1-hot 8KB tile). LDS
// keeps only lane-varying k4 (1 read/quad). kq ping-pong: 1 barrier/chunk,
// Ek prefetched 2 chunks ahead. Math bit-identical to R3.
// Grid 1024 blocks (4/CU); b = bid&7 for XCD L2 affinity on Ek.
// ---------------------------------------------------------------------------
__global__ __launch_bounds__(256) void logits_kernel(
    const float* __restrict__ Eq, const float* __restrict__ Ek,
    const float* __restrict__ wl, float* __restrict__ sr) {
    const int bid = blockIdx.x;
    const int b  = bid & 7;
    const int r2 = bid >> 3;
    const int mt = r2 & 7;      // m tile of 128
    const int qt = r2 >> 3;     // q octet
    const int tid = threadIdx.x;
    const int m  = tid & 127;
    const int qh = __builtin_amdgcn_readfirstlane(tid >> 7);  // wave-uniform

    __shared__ float kq[2][4][128][4];   // [buf][h-quad][m][4]

    const float* qpb = Eq + ((size_t)(b * QL_ + qt * 8 + qh * 4)) * H_;  // 4 q rows
    const float* kpb = Ek + ((size_t)(b * ML_ + mt * 128)) * H_;

    // Ek staging map: lane covers row srow, h-range [8*sq2, 8*sq2+8) of chunk
    const int srow = tid & 127;
    const int sq2  = tid >> 7;
    const float* kst = kpb + (size_t)srow * H_ + 8 * sq2;

    // prologue: chunk0 -> buf0; prefetch chunk1 into regs
    float4 a0 = *(const float4*)(kst);
    float4 a1 = *(const float4*)(kst + 4);
    *(float4*)(&kq[0][2 * sq2 + 0][srow][0]) = a0;
    *(float4*)(&kq[0][2 * sq2 + 1][srow][0]) = a1;
    a0 = *(const float4*)(kst + 16);
    a1 = *(const float4*)(kst + 20);
    __syncthreads();

    float acc[4] = {0.f, 0.f, 0.f, 0.f};

    for (int c = 0; c < 16; ++c) {
        const int cb = c & 1;
        if (c < 15) {                       // stage chunk c+1 into other buf
            *(float4*)(&kq[cb ^ 1][2 * sq2 + 0][srow][0]) = a0;
            *(float4*)(&kq[cb ^ 1][2 * sq2 + 1][srow][0]) = a1;
            if (c < 14) {                   // prefetch chunk c+2 (2 ahead)
                a0 = *(const float4*)(kst + (c + 2) * 16);
                a1 = *(const float4*)(kst + (c + 2) * 16 + 4);
            }
        }
        const int h0 = c * 16;
#pragma unroll
        for (int quad = 0; quad < 4; ++quad) {
            float4 k4 = *(const float4*)(&kq[cb][quad][m][0]);
            float4 w4 = *(const float4*)(wl + h0 + quad * 4);          // uniform
#pragma unroll
            for (int j2 = 0; j2 < 4; ++j2) {
                float4 q4 = *(const float4*)(qpb + (size_t)j2 * H_ + h0 + quad * 4);
                float p0 = fmaf(k4.x, q4.x, 1.0f);
                float p1 = fmaf(k4.y, q4.y, 1.0f);
                float p2 = fmaf(k4.z, q4.z, 1.0f);
                float p3 = fmaf(k4.w, q4.w, 1.0f);
                float p01 = p0 * p1, p23 = p2 * p3;
                float n01 = fmaf(w4.y, p0, w4.x * p1);
                float n23 = fmaf(w4.w, p2, w4.z * p3);
                float Nm  = fmaf(n23, p01, n01 * p23);
                float P   = p01 * p23;
                acc[j2] = fmaf(Nm, __builtin_amdgcn_rcpf(P), acc[j2]);
            }
        }
        __syncthreads();
    }
#pragma unroll
    for (int j2 = 0; j2 < 4; ++j2)
        sr[((size_t)(b * QL_ + qt * 8 + qh * 4 + j2)) * ML_ + mt * 128 + m] = acc[j2];
}

// ---------------------------------------------------------------------------
// In-place masked softmax (unchanged). logits_eff = -2*sr (shift-invariant).
// ---------------------------------------------------------------------------
__global__ __launch_bounds__(256) void softmax_kernel(
    float* __restrict__ wrow_io, const unsigned char* __restrict__ mv) {
    const int row = blockIdx.x;
    const int b = row >> 7;
    const int tid = threadIdx.x;
    float* srow = wrow_io + (size_t)row * ML_;
    const unsigned char* mrow = mv + b * ML_;
    __shared__ float red[4];

    float4 s4 = *(const float4*)(srow + tid * 4);
    uchar4 m4 = *(const uchar4*)(mrow + tid * 4);
    float l[4];
    l[0] = m4.x ? -1e18f : -2.0f * s4.x;
    l[1] = m4.y ? -1e18f : -2.0f * s4.y;
    l[2] = m4.z ? -1e18f : -2.0f * s4.z;
    l[3] = m4.w ? -1e18f : -2.0f * s4.w;

    float mx = fmaxf(fmaxf(l[0], l[1]), fmaxf(l[2], l[3]));
#pragma unroll
    for (int off = 32; off >= 1; off >>= 1)
        mx = fmaxf(mx, __shfl_xor(mx, off));
    if ((tid & 63) == 0) red[tid >> 6] = mx;
    __syncthreads();
    mx = fmaxf(fmaxf(red[0], red[1]), fmaxf(red[2], red[3]));
    __syncthreads();

    const float L2E = 1.44269504088896340736f;
    float e[4], s = 0.f;
#pragma unroll
    for (int i = 0; i < 4; ++i) {
        e[i] = __builtin_amdgcn_exp2f((l[i] - mx) * L2E);
        s += e[i];
    }
#pragma unroll
    for (int off = 32; off >= 1; off >>= 1)
        s += __shfl_xor(s, off);
    if ((tid & 63) == 0) red[tid >> 6] = s;
    __syncthreads();
    s = (red[0] + red[1]) + (red[2] + red[3]);
    float inv = __builtin_amdgcn_rcpf(s);
    float4 o = make_float4(e[0] * inv, e[1] * inv, e[2] * inv, e[3] * inv);
    *(float4*)(srow + tid * 4) = o;
}

// ---------------------------------------------------------------------------
// attns[b] = W[b] (128x1024) @ M[b] (1024x512). LDS-tiled GEMM (unchanged).
// ---------------------------------------------------------------------------
__global__ __launch_bounds__(256) void attn_out_kernel(
    const float* __restrict__ wgt, const float* __restrict__ mem,
    float* __restrict__ out) {
    const int bid = blockIdx.x;
    const int b  = bid & 7;
    const int j2 = bid >> 3;
    const int mt = j2 & 3;
    const int nt = j2 >> 2;
    const int t = threadIdx.x;
    __shared__ float As[32][34];
    __shared__ float Bs[32][64];

    const int ar = t >> 3, ac = (t & 7) << 2;
    const int br = t >> 4, bc = (t & 15) << 2;
    const float* Ap = wgt + ((size_t)(b * QL_ + mt * 32 + ar)) * ML_ + ac;
    const float* Bp = mem + ((size_t)(b * ML_ + br)) * KS_ + nt * 64 + bc;

    const int tx = t & 15, ty = t >> 4;
    float acc0[4] = {0.f, 0.f, 0.f, 0.f};
    float acc1[4] = {0.f, 0.f, 0.f, 0.f};

    float4 apre = *(const float4*)(Ap);
    float4 bpre0 = *(const float4*)(Bp);
    float4 bpre1 = *(const float4*)(Bp + (size_t)16 * KS_);

    for (int k0 = 0; k0 < ML_; k0 += 32) {
        __syncthreads();
        As[ac + 0][ar] = apre.x; As[ac + 1][ar] = apre.y;
        As[ac + 2][ar] = apre.z; As[ac + 3][ar] = apre.w;
        *(float4*)(&Bs[br][bc])      = bpre0;
        *(float4*)(&Bs[br + 16][bc]) = bpre1;
        __syncthreads();
        if (k0 + 32 < ML_) {
            apre  = *(const float4*)(Ap + k0 + 32);
            bpre0 = *(const float4*)(Bp + (size_t)(k0 + 32) * KS_);
            bpre1 = *(const float4*)(Bp + (size_t)(k0 + 48) * KS_);
        }
#pragma unroll
        for (int kk = 0; kk < 32; ++kk) {
            float2 a2 = *(const float2*)(&As[kk][ty * 2]);
            float4 b4 = *(const float4*)(&Bs[kk][tx * 4]);
            acc0[0] = fmaf(a2.x, b4.x, acc0[0]);
            acc0[1] = fmaf(a2.x, b4.y, acc0[1]);
            acc0[2] = fmaf(a2.x, b4.z, acc0[2]);
            acc0[3] = fmaf(a2.x, b4.w, acc0[3]);
            acc1[0] = fmaf(a2.y, b4.x, acc1[0]);
            acc1[1] = fmaf(a2.y, b4.y, acc1[1]);
            acc1[2] = fmaf(a2.y, b4.z, acc1[2]);
            acc1[3] = fmaf(a2.y, b4.w, acc1[3]);
        }
    }
    size_t orow = ((size_t)(b * QL_ + mt * 32 + ty * 2)) * KS_ + nt * 64 + tx * 4;
    *(float4*)(out + orow)       = make_float4(acc0[0], acc0[1], acc0[2], acc0[3]);
    *(float4*)(out + orow + KS_) = make_float4(acc1[0], acc1[1], acc1[2], acc1[3]);
}

extern "C" void kernel_launch(void* const* d_in, const int* in_sizes, int n_in,
                              void* d_out, int out_size, void* d_ws, size_t ws_size,
                              hipStream_t stream) {
    const float* query  = (const float*)d_in[0];
    const float* memory = (const float*)d_in[1];
    const unsigned char* mask = (const unsigned char*)d_in[2];
    const float* Wq = (const float*)d_in[3];
    const float* bq = (const float*)d_in[4];
    const float* Wk = (const float*)d_in[5];
    const float* bk = (const float*)d_in[6];
    const float* wl = (const float*)d_in[7];
    // d_in[8] (bl) cancels under softmax shift-invariance; not read.

    float* ws = (float*)d_ws;
    float* Eq = ws + QP_OFF;
    float* Ek = ws + KP_OFF;
    unsigned char* mcan = (unsigned char*)(ws + MASK_OFF);
    unsigned short* Whi = (unsigned short*)(ws + WH_OFF);
    unsigned short* Wlo = (unsigned short*)(ws + WL_OFF);
    unsigned short* Xhi = (unsigned short*)(ws + XH_OFF);
    unsigned short* Xlo = (unsigned short*)(ws + XL_OFF);

    float* attns = (float*)d_out;                      // [B][QL][KS]
    float* wout  = (float*)d_out + B_ * QL_ * KS_;     // [B][QL][ML] (also sr scratch)

    prep_kernel<<<dim3(1217), dim3(256), 0, stream>>>(query, memory, Wq, Wk,
                                                      Whi, Wlo, Xhi, Xlo, mask, mcan);
    proj_kernel<<<dim3(576), dim3(256), 0, stream>>>(Xhi, Xlo, Whi, Wlo,
                                                     bq, bk, Eq, Ek);
    logits_kernel<<<dim3(1024), dim3(256), 0, stream>>>(Eq, Ek, wl, wout);
    softmax_kernel<<<dim3(B_ * QL_), dim3(256), 0, stream>>>(wout, mcan);
    attn_out_kernel<<<dim3(256), dim3(256), 0, stream>>>(wout, memory, attns);
}